// Round 2
// baseline (351.329 us; speedup 1.0000x reference)
//
#include <hip/hip_runtime.h>
#include <math.h>

typedef float vf4 __attribute__((ext_vector_type(4)));

constexpr int T = 8192;
constexpr int D = 128;
constexpr int N = 32;
constexpr int L = 64;            // chunk length
constexpr int LOG2L = 6;         // log2(L)
constexpr int K = T / L;         // 128 chunks
constexpr int S = N * D;         // 4096 state elements
constexpr int S4 = S / 4;        // 1024 float4 states
constexpr int D4 = D / 4;        // 32
constexpr int OSTRIDE4 = (2 * N * D) / 4;  // 2048 float4 per output time-row

__device__ __forceinline__ float fast_sqrt(float x) {
    float r;
    asm("v_sqrt_f32 %0, %1" : "=v"(r) : "v"(x));
    return r;
}

// ---------------------------------------------------------------------------
// k1: one walk per (chunk k, state s4) computing three chunk summaries:
//   q (=c_a)  : chunk-local EMA contribution  q_{i+1} = q + a*(x_i - q)
//   A         : A_{i+1} = b*(A + a*p_i^2),  p_i = x_i - q_i  (pre-update q)
//   P         : sum p_i
// c_v is then A - 2*(a*b^L*P)*H + b^L(1-b^L)*H^2  (H = h_a at chunk start),
// so the variance scan needs no second walk over x.
// Derivation: h_a^(i) = b^i H + q_i;  d_i = p_i - b^i H;
//   c_v = sum_i b^(L-i) a d_i^2 expands into the three H-free summaries.
// ---------------------------------------------------------------------------
__global__ __launch_bounds__(256) void k1_summaries(
    const vf4* __restrict__ x, const vf4* __restrict__ alpha,
    vf4* __restrict__ c_a, vf4* __restrict__ cA, vf4* __restrict__ cP)
{
    int gid = blockIdx.x * 256 + threadIdx.x;   // [0, K*S4)
    int k   = gid >> 10;                        // gid / S4
    int s4  = gid & (S4 - 1);
    int d4  = s4 & (D4 - 1);

    vf4 a = alpha[s4];
    vf4 b = 1.0f - a;
    vf4 q = {0.f, 0.f, 0.f, 0.f};
    vf4 A = {0.f, 0.f, 0.f, 0.f};
    vf4 P = {0.f, 0.f, 0.f, 0.f};
    const vf4* xp = x + (size_t)k * L * D4 + d4;
#pragma unroll 8
    for (int i = 0; i < L; ++i) {
        vf4 xv = xp[(size_t)i * D4];
        vf4 p  = xv - q;          // p_i uses q BEFORE update
        P += p;
        A = b * (A + (a * p) * p);
        q = q + a * p;            // == b*q + a*x
    }
    c_a[gid] = q;
    cA[gid]  = A;
    cP[gid]  = P;
}

// ---------------------------------------------------------------------------
// k2: ONE merged scan over chunks: scans h_a, synthesizes c_v from (A,P,H)
//     closed form, scans h_v in the same loop. Writes both *_start arrays and
//     both output tails. 16 blocks x 64 spreads latency-bound loads over 16
//     CUs; unroll-8 batches 24 address-independent loads per latency exposure.
//     h_v is clamped to >=0 at every escape point: the expanded c_v can round
//     tiny-negative when the true value ~0, and sqrt(negative) = NaN.
// ---------------------------------------------------------------------------
__global__ __launch_bounds__(64) void k2_scan(
    const vf4* __restrict__ h_a0, const vf4* __restrict__ h_sd0,
    const vf4* __restrict__ alpha,
    const vf4* __restrict__ c_a, const vf4* __restrict__ cA,
    const vf4* __restrict__ cP,
    vf4* __restrict__ h_a_start, vf4* __restrict__ h_v_start,
    float* __restrict__ out)
{
    int s4 = blockIdx.x * 64 + threadIdx.x;     // [0, S4)
    vf4 a = alpha[s4];
    vf4 b = 1.0f - a;
    vf4 bl = b;
#pragma unroll
    for (int i = 0; i < LOG2L; ++i) bl *= bl;   // beta^L
    vf4 Cq = bl * (1.0f - bl);                  // C = b^L (1 - b^L)
    vf4 Bc = a * bl;                            // B = a b^L (times P)

    vf4 ha = h_a0[s4];
    vf4 sd = h_sd0[s4];
    vf4 hv = sd * sd;
#pragma unroll 8
    for (int k = 0; k < K; ++k) {
        size_t idx = (size_t)k * S4 + s4;
        vf4 ca = c_a[idx];
        vf4 Ak = cA[idx];
        vf4 Pk = cP[idx];
        h_a_start[idx] = ha;
        vf4 hvc;
#pragma unroll
        for (int j = 0; j < 4; ++j) hvc[j] = fmaxf(hv[j], 0.f);
        h_v_start[idx] = hvc;
        vf4 cv = Ak - 2.0f * ((Bc * Pk) * ha) + Cq * (ha * ha);
        ha = bl * ha + ca;
        hv = bl * hvc + cv;
    }
    // tails: hN_a then sqrt(hN_v)
    vf4* tail = (vf4*)(out + (size_t)T * 2 * N * D);
    tail[s4] = ha;
    vf4 r;
#pragma unroll
    for (int j = 0; j < 4; ++j) r[j] = fast_sqrt(fmaxf(hv[j], 0.f));
    tail[S4 + s4] = r;
}

// ---------------------------------------------------------------------------
// k3: single fused output walk. Evolves h and v together from their true
//     chunk starts; writes the out_a row AND the sqrt(out_v) row per step.
//     Replaces the old k3+k5 pair; total output streamed exactly once.
//     Writes are wave-coalesced: consecutive lanes = consecutive s4 = one
//     contiguous 1 KiB store per instruction.
// ---------------------------------------------------------------------------
__global__ __launch_bounds__(256) void k3_fused(
    const vf4* __restrict__ x, const vf4* __restrict__ alpha,
    const vf4* __restrict__ h_a_start, const vf4* __restrict__ h_v_start,
    vf4* __restrict__ out)
{
    int gid = blockIdx.x * 256 + threadIdx.x;
    int k   = gid >> 10;
    int s4  = gid & (S4 - 1);
    int n   = s4 >> 5;              // s4 / D4
    int d4  = s4 & (D4 - 1);

    vf4 a = alpha[s4];
    vf4 b = 1.0f - a;
    vf4 h = h_a_start[gid];
    vf4 v = h_v_start[gid];
    const vf4* xp = x + (size_t)k * L * D4 + d4;
    vf4* opa = out + (size_t)k * L * OSTRIDE4 + n * D4 + d4;
    vf4* opv = opa + N * D4;        // 16 KB into the same time row
#pragma unroll 8
    for (int i = 0; i < L; ++i) {
        vf4 xv  = xp[(size_t)i * D4];
        vf4 dx  = xv - h;           // uses OLD h (matches reference order)
        vf4 adx = a * dx;
        v = b * (v + adx * dx);
        h = h + adx;
        vf4 r;
#pragma unroll
        for (int j = 0; j < 4; ++j) r[j] = fast_sqrt(v[j]);
        opa[(size_t)i * OSTRIDE4] = h;
        opv[(size_t)i * OSTRIDE4] = r;
    }
}

// ---------------------------------------------------------------------------
extern "C" void kernel_launch(void* const* d_in, const int* in_sizes, int n_in,
                              void* d_out, int out_size, void* d_ws, size_t ws_size,
                              hipStream_t stream) {
    const vf4* x     = (const vf4*)d_in[0];   // (T, D) fp32
    const vf4* h_a0  = (const vf4*)d_in[1];   // (N, D)
    const vf4* h_sd0 = (const vf4*)d_in[2];   // (N, D)
    const vf4* alpha = (const vf4*)d_in[3];   // (N, D)
    float* out = (float*)d_out;               // (T,2N,D) + hN_a (N,D) + hN_sd (N,D)
    float* ws  = (float*)d_ws;

    // workspace layout (floats): 5 arrays of K*S = 512K floats (10.5 MB total)
    vf4* c_a       = (vf4*)(ws + 0 * (size_t)K * S);
    vf4* cA        = (vf4*)(ws + 1 * (size_t)K * S);
    vf4* cP        = (vf4*)(ws + 2 * (size_t)K * S);
    vf4* h_a_start = (vf4*)(ws + 3 * (size_t)K * S);
    vf4* h_v_start = (vf4*)(ws + 4 * (size_t)K * S);

    dim3 big(K * S4 / 256);   // 512 blocks
    dim3 blk(256);

    k1_summaries<<<big, blk, 0, stream>>>(x, alpha, c_a, cA, cP);
    k2_scan<<<dim3(S4 / 64), dim3(64), 0, stream>>>(h_a0, h_sd0, alpha,
                                                    c_a, cA, cP,
                                                    h_a_start, h_v_start, out);
    k3_fused<<<big, blk, 0, stream>>>(x, alpha, h_a_start, h_v_start, (vf4*)out);
}

// Round 4
// 293.459 us; speedup vs baseline: 1.1972x; 1.1972x over previous
//
#include <hip/hip_runtime.h>
#include <math.h>

typedef float vf4 __attribute__((ext_vector_type(4)));

constexpr int T = 8192;
constexpr int D = 128;
constexpr int N = 32;
constexpr int L = 32;            // sub-chunk length (halved: 2x parallelism in k1/k3)
constexpr int LOG2L = 5;         // log2(L)
constexpr int K = T / L;         // 256 chunks
constexpr int S = N * D;         // 4096 state elements
constexpr int S4 = S / 4;        // 1024 float4 states
constexpr int D4 = D / 4;        // 32
constexpr int OSTRIDE4 = (2 * N * D) / 4;  // 2048 float4 per output time-row

// k2 segmented-scan geometry: each block owns COLS state columns over all K
// chunks, split into SEG segments of CPS chunks walked serially per thread.
constexpr int SEG  = 8;          // segments per column
constexpr int CPS  = K / SEG;    // 32 chunks per segment
constexpr int COLS = 32;         // columns per block (COLS*SEG = 256 threads)

__device__ __forceinline__ float fast_sqrt(float x) {
    float r;
    asm("v_sqrt_f32 %0, %1" : "=v"(r) : "v"(x));
    return r;
}

// ---------------------------------------------------------------------------
// k1: per (chunk k, state s4), walk L steps of x computing H-free summaries:
//   q (=c_a): chunk-local EMA   q' = q + a*(x - q)          (q0 = 0)
//   A:        A' = b*(A + a*p^2),  p = x - q (pre-update q)
//   P:        sum of p
// Then c_v(H) = A - 2*(a*b^L)*P*H + b^L(1-b^L)*H^2 exactly (verified for
// L=1,2 by expansion; cross terms telescope because b^(L-i)*b^i = b^L).
// ---------------------------------------------------------------------------
__global__ __launch_bounds__(256) void k1_summaries(
    const vf4* __restrict__ x, const vf4* __restrict__ alpha,
    vf4* __restrict__ c_a, vf4* __restrict__ cA, vf4* __restrict__ cP)
{
    int gid = blockIdx.x * 256 + threadIdx.x;   // [0, K*S4) = [0, 262144)
    int k   = gid >> 10;                        // gid / S4
    int s4  = gid & (S4 - 1);
    int d4  = s4 & (D4 - 1);

    vf4 a = alpha[s4];
    vf4 b = 1.0f - a;
    vf4 q = {0.f, 0.f, 0.f, 0.f};
    vf4 A = {0.f, 0.f, 0.f, 0.f};
    vf4 P = {0.f, 0.f, 0.f, 0.f};
    const vf4* xp = x + (size_t)k * L * D4 + d4;
#pragma unroll 8
    for (int i = 0; i < L; ++i) {
        vf4 xv = xp[(size_t)i * D4];
        vf4 p  = xv - q;          // p uses q BEFORE update
        P += p;
        A = b * (A + (a * p) * p);
        q = q + a * p;
    }
    c_a[gid] = q;
    cA[gid]  = A;
    cP[gid]  = P;
}

// ---------------------------------------------------------------------------
// k2: segmented scan over chunks, fully in-block (2 __syncthreads, no serial
// K-length chain). Block = COLS columns x SEG segments; each thread walks
// CPS=32 chunks serially.
//   pass1: aggregate c_a per segment            -> LDS
//          fold h_a segment starts from h_a0  (<=7 affine steps, M = bl^CPS)
//   pass2: rewalk: emit h_a_start (in-place over c_a), synthesize c_v from
//          (A,P,H) closed form, aggregate c_v per segment -> LDS
//          fold h_v segment starts from h_sd0^2
//   pass3: rewalk: emit h_v_start (clamped >=0, in-place over cA)
// Buffers after k2: buf0 = h_a_start, buf1 = h_v_start. Tails written by the
// kg==SEG-1 threads (their end-of-segment state is the global final state).
// In-place safety: every (chunk,s4) index is owned by exactly ONE thread in
// all passes; loads precede stores thread-locally; Vagg dependency is behind
// a __syncthreads.
// ---------------------------------------------------------------------------
__global__ __launch_bounds__(256) void k2_scan(
    const vf4* __restrict__ h_a0, const vf4* __restrict__ h_sd0,
    const vf4* __restrict__ alpha,
    vf4* __restrict__ buf0,          // in: c_a   out: h_a_start
    vf4* __restrict__ buf1,          // in: cA    out: h_v_start
    const vf4* __restrict__ buf2,    // cP
    float* __restrict__ out)
{
    __shared__ vf4 Cagg[SEG][COLS];
    __shared__ vf4 Vagg[SEG][COLS];

    int t   = threadIdx.x;
    int col = t & (COLS - 1);
    int kg  = t >> 5;                        // segment index [0, SEG)
    int s4  = blockIdx.x * COLS + col;       // [0, S4)
    int kbase = kg * CPS;

    vf4 a = alpha[s4];
    vf4 b = 1.0f - a;
    vf4 bl = b;
#pragma unroll
    for (int i = 0; i < LOG2L; ++i) bl *= bl;   // b^L (per-chunk multiplier)
    vf4 M = bl;
#pragma unroll
    for (int i = 0; i < 5; ++i) M *= M;         // bl^CPS (per-segment multiplier)
    vf4 Cq = bl * (1.0f - bl);
    vf4 Bc = a * bl;

    // ---- pass 1: segment aggregate of c_a ----
    vf4 C = {0.f, 0.f, 0.f, 0.f};
#pragma unroll 4
    for (int j = 0; j < CPS; ++j) {
        vf4 ca = buf0[(size_t)(kbase + j) * S4 + s4];
        C = bl * C + ca;
    }
    Cagg[kg][col] = C;
    __syncthreads();

    // fold h_a start for this segment: H = fold(h_a0 through segments < kg)
    vf4 H = h_a0[s4];
    for (int g = 0; g < kg; ++g) H = M * H + Cagg[g][col];

    // ---- pass 2: rewalk; write h_a_start; aggregate c_v ----
    vf4 Vg = {0.f, 0.f, 0.f, 0.f};
#pragma unroll 4
    for (int j = 0; j < CPS; ++j) {
        size_t idx = (size_t)(kbase + j) * S4 + s4;
        vf4 ca = buf0[idx];
        vf4 Ak = buf1[idx];
        vf4 Pk = buf2[idx];
        buf0[idx] = H;                          // h_a_start (pre-update)
        vf4 cv = Ak - 2.0f * ((Bc * Pk) * H) + Cq * (H * H);
        Vg = bl * Vg + cv;
        H  = bl * H + ca;
    }
    Vagg[kg][col] = Vg;
    if (kg == SEG - 1) {                        // H is now hN_a
        vf4* tail = (vf4*)(out + (size_t)T * 2 * N * D);
        tail[s4] = H;
    }
    __syncthreads();

    // fold h_v start for this segment
    vf4 sd = h_sd0[s4];
    vf4 V = sd * sd;
    for (int g = 0; g < kg; ++g) V = M * V + Vagg[g][col];

    // ---- pass 3: rewalk; write h_v_start (clamped) ----
#pragma unroll 4
    for (int j = 0; j < CPS; ++j) {
        size_t idx = (size_t)(kbase + j) * S4 + s4;
        vf4 Hk = buf0[idx];                     // h_a_start (just written)
        vf4 Ak = buf1[idx];
        vf4 Pk = buf2[idx];
        vf4 Vc;
#pragma unroll
        for (int jj = 0; jj < 4; ++jj) Vc[jj] = fmaxf(V[jj], 0.f);
        buf1[idx] = Vc;                         // h_v_start (pre-update)
        vf4 cv = Ak - 2.0f * ((Bc * Pk) * Hk) + Cq * (Hk * Hk);
        V = bl * Vc + cv;
    }
    if (kg == SEG - 1) {                        // V is now hN_v
        vf4* tail = (vf4*)(out + (size_t)T * 2 * N * D);
        vf4 r;
#pragma unroll
        for (int jj = 0; jj < 4; ++jj) r[jj] = fast_sqrt(fmaxf(V[jj], 0.f));
        tail[S4 + s4] = r;
    }
}

// ---------------------------------------------------------------------------
// k3: fused output walk. Evolves (h, v) from true chunk starts, writes the
// out_a row and sqrt(out_v) row per step with NONTEMPORAL stores (output is
// write-once; keep it out of L2 so x / h-start arrays stay resident).
// v stays >= 0 within the walk (v' = b*(v + a*dx^2), both terms >= 0), so
// sqrt is safe given the clamped h_v_start.
// ---------------------------------------------------------------------------
__global__ __launch_bounds__(256) void k3_fused(
    const vf4* __restrict__ x, const vf4* __restrict__ alpha,
    const vf4* __restrict__ h_a_start, const vf4* __restrict__ h_v_start,
    vf4* __restrict__ out)
{
    int gid = blockIdx.x * 256 + threadIdx.x;   // [0, K*S4)
    int k   = gid >> 10;
    int s4  = gid & (S4 - 1);
    int n   = s4 >> 5;              // s4 / D4
    int d4  = s4 & (D4 - 1);

    vf4 a = alpha[s4];
    vf4 b = 1.0f - a;
    vf4 h = h_a_start[gid];
    vf4 v = h_v_start[gid];
    const vf4* xp = x + (size_t)k * L * D4 + d4;
    vf4* opa = out + (size_t)k * L * OSTRIDE4 + n * D4 + d4;
    vf4* opv = opa + N * D4;        // 16 KB into the same time row
#pragma unroll 8
    for (int i = 0; i < L; ++i) {
        vf4 xv  = xp[(size_t)i * D4];
        vf4 dx  = xv - h;           // uses OLD h (matches reference order)
        vf4 adx = a * dx;
        v = b * (v + adx * dx);
        h = h + adx;
        vf4 r;
#pragma unroll
        for (int j = 0; j < 4; ++j) r[j] = fast_sqrt(v[j]);
        __builtin_nontemporal_store(h, &opa[(size_t)i * OSTRIDE4]);
        __builtin_nontemporal_store(r, &opv[(size_t)i * OSTRIDE4]);
    }
}

// ---------------------------------------------------------------------------
extern "C" void kernel_launch(void* const* d_in, const int* in_sizes, int n_in,
                              void* d_out, int out_size, void* d_ws, size_t ws_size,
                              hipStream_t stream) {
    const vf4* x     = (const vf4*)d_in[0];   // (T, D) fp32
    const vf4* h_a0  = (const vf4*)d_in[1];   // (N, D)
    const vf4* h_sd0 = (const vf4*)d_in[2];   // (N, D)
    const vf4* alpha = (const vf4*)d_in[3];   // (N, D)
    float* out = (float*)d_out;               // (T,2N,D) + hN_a (N,D) + hN_sd (N,D)
    float* ws  = (float*)d_ws;

    // workspace: 3 arrays of K*S floats = 4 MB each (12 MB total).
    // buf0: c_a -> h_a_start (in-place in k2); buf1: cA -> h_v_start; buf2: cP.
    vf4* buf0 = (vf4*)(ws + 0 * (size_t)K * S);
    vf4* buf1 = (vf4*)(ws + 1 * (size_t)K * S);
    vf4* buf2 = (vf4*)(ws + 2 * (size_t)K * S);

    dim3 big(K * S4 / 256);   // 1024 blocks
    dim3 blk(256);

    k1_summaries<<<big, blk, 0, stream>>>(x, alpha, buf0, buf1, buf2);
    k2_scan<<<dim3(S4 / COLS), blk, 0, stream>>>(h_a0, h_sd0, alpha,
                                                 buf0, buf1, buf2, out);
    k3_fused<<<big, blk, 0, stream>>>(x, alpha, buf0, buf1, (vf4*)out);
}